// Round 15
// baseline (556.562 us; speedup 1.0000x reference)
//
#include <hip/hip_runtime.h>
#include <hip/hip_bf16.h>

// Problem constants (fixed by the reference)
#define NN 150000      // nodes
#define EE 600000      // edges
#define F_IN 32        // input node features
#define HD 128         // hidden dim
#define GG 2048        // graphs
#define CAP 28         // max degree bucket capacity (Poisson(4): P(deg>=28) ~ 4e-18)
#define NP 150016      // NN rounded up to 128-node blocks: 1172*128

typedef __attribute__((ext_vector_type(8))) short bf16x8;
typedef __attribute__((ext_vector_type(4))) float f32x4;

__device__ inline void split_bf16(float v, unsigned short& hi, unsigned short& lo) {
    __hip_bfloat16 h = __float2bfloat16(v);
    float hv = __bfloat162float(h);
    __hip_bfloat16 l = __float2bfloat16(v - hv);
    hi = *reinterpret_cast<unsigned short*>(&h);
    lo = *reinterpret_cast<unsigned short*>(&l);
}
__device__ inline unsigned short bf16_hi(float v) {
    __hip_bfloat16 h = __float2bfloat16(v);
    return *reinterpret_cast<unsigned short*>(&h);
}
__device__ inline unsigned short bf16_lo(float v) {
    __hip_bfloat16 h = __float2bfloat16(v);
    float hv = __bfloat162float(h);
    __hip_bfloat16 l = __float2bfloat16(v - hv);
    return *reinterpret_cast<unsigned short*>(&l);
}
__device__ inline float bf2f(unsigned short u) {
    union { unsigned int i; float f; } c;
    c.i = ((unsigned int)u) << 16;
    return c.f;
}

// ---------------------------------------------------------------------------
// Zero-init for workspace regions
// ---------------------------------------------------------------------------
__global__ void init_zero(int* __restrict__ cnt_node, int* __restrict__ cntg,
                          float* __restrict__ pooled) {
    int i = blockIdx.x * blockDim.x + threadIdx.x;
    if (i < NN) cnt_node[i] = 0;
    if (i < GG) cntg[i] = 0;
    if (i < GG * HD) pooled[i] = 0.f;
}

// ---------------------------------------------------------------------------
// x (fp32) -> bf16 rows: makes layer-0 gather rows 64B (1 sector).
// ---------------------------------------------------------------------------
__global__ void convert_x(const float* __restrict__ x, unsigned short* __restrict__ xb) {
    int i = blockIdx.x * blockDim.x + threadIdx.x;   // one per 8 elements
    if (i >= NN * F_IN / 8) return;
    const float* s = x + (size_t)i * 8;
    float4 v0 = *(const float4*)s;
    float4 v1 = *(const float4*)(s + 4);
    bf16x8 o;
    o[0] = (short)bf16_hi(v0.x); o[1] = (short)bf16_hi(v0.y);
    o[2] = (short)bf16_hi(v0.z); o[3] = (short)bf16_hi(v0.w);
    o[4] = (short)bf16_hi(v1.x); o[5] = (short)bf16_hi(v1.y);
    o[6] = (short)bf16_hi(v1.z); o[7] = (short)bf16_hi(v1.w);
    *(bf16x8*)(xb + (size_t)i * 8) = o;
}

// ---------------------------------------------------------------------------
// CSR-bucket build + per-graph node counts (fused)
// ---------------------------------------------------------------------------
__global__ void build_graph(const int* __restrict__ ei, const int* __restrict__ batch,
                            int* __restrict__ cnt_node, int* __restrict__ cntg,
                            int* __restrict__ bucket) {
    int e = blockIdx.x * blockDim.x + threadIdx.x;
    if (e < NN) atomicAdd(&cntg[batch[e]], 1);
    if (e >= EE) return;
    int src = ei[e];         // edge_index[0]
    int dst = ei[EE + e];    // edge_index[1]
    int slot = atomicAdd(&cnt_node[dst], 1);
    if (slot < CAP) bucket[dst * CAP + slot] = src;
}

// ---------------------------------------------------------------------------
// Weight prep: fp32 W[K][H] -> split-bf16 packed in LANE-LINEAR fragment order
// ---------------------------------------------------------------------------
struct PrepDesc { const float* src; unsigned short* dhi; unsigned short* dlo; int K; };
struct PrepArgs { PrepDesc d[9]; };

__global__ void prep_weights(PrepArgs pa) {
    PrepDesc de = pa.d[blockIdx.y];
    int total = de.K * HD;
    int KS = de.K >> 5;
    for (int idx = blockIdx.x * blockDim.x + threadIdx.x; idx < total;
         idx += gridDim.x * blockDim.x) {
        int k = idx / HD, h = idx - (idx / HD) * HD;   // src is [K][H]
        unsigned short hi, lo;
        split_bf16(de.src[idx], hi, lo);
        int nt = h >> 4, m = h & 15;
        int ks = k >> 5, quad = (k >> 3) & 3, e = k & 7;
        int lane = quad * 16 + m;
        int pidx = ((nt * KS + ks) * 64 + lane) * 8 + e;
        de.dhi[pidx] = hi;
        de.dlo[pidx] = lo;
    }
}

// ---------------------------------------------------------------------------
// Fused GIN layer: gather-aggregate (fp32 accumulate, bf16 rows) + 3-layer
// MLP on the matrix pipe, split-bf16: D = Ah*Bh + Al*Bh + Ah*Bl.
//
// Gather service rate is pinned at ~5.3G rows/s device-wide — invariant
// across row bytes (512/256), unroll (2/4/8), registers, occupancy, chain
// depth, and request granularity (R5..R14 falsification record). This kernel
// sits at the empirical optimum: bf16 rows, UN=4 (8 for K=32), VGPR 84,
// launch_bounds(256,3), plain cached stores, POOL fuses the mean-pool.
// ---------------------------------------------------------------------------
template <int K_IN, bool POOL>
__launch_bounds__(256, 3)
__global__ void gin_layer(const unsigned short* __restrict__ hb,
                          const int* __restrict__ cnt_node,
                          const int* __restrict__ bucket,
                          const unsigned short* __restrict__ w1h, const unsigned short* __restrict__ w1l,
                          const float* __restrict__ b1,
                          const unsigned short* __restrict__ w2h, const unsigned short* __restrict__ w2l,
                          const float* __restrict__ b2,
                          const unsigned short* __restrict__ w3h, const unsigned short* __restrict__ w3l,
                          const float* __restrict__ b3,
                          unsigned short* __restrict__ out,   // bf16 activations (non-pool)
                          const int* __restrict__ batch,
                          float* __restrict__ pooled) {
    constexpr int KS1 = K_IN / 32;
    constexpr int UN = (KS1 == 1) ? 8 : 4;   // gather unroll depth (bf16 rows)
    __shared__ unsigned short sh[4][32][HD + 8];   // 34816 B / block

    const int wave = threadIdx.x >> 6;
    const int lane = threadIdx.x & 63;
    const int m = lane & 15;      // node row within a 16-set / out-feature col
    const int quad = lane >> 4;   // 0..3
    const int nodeBase = blockIdx.x * 128 + wave * 32;

    // ---- fused aggregation: self + neighbors, fp32 -> split-bf16 A frags ----
    bf16x8 ah[2][KS1], al[2][KS1];
#pragma unroll
    for (int s = 0; s < 2; s++) {
        int node = nodeBase + s * 16 + m;
        node = node < NN ? node : NN - 1;
        float ag[KS1][8];
        {
            const unsigned short* rs = hb + (size_t)node * K_IN + quad * 8;
#pragma unroll
            for (int ks = 0; ks < KS1; ks++) {
                bf16x8 v = *(const bf16x8*)(rs + ks * 32);
#pragma unroll
                for (int e = 0; e < 8; e++) ag[ks][e] = bf2f((unsigned short)v[e]);
            }
        }
        int cnt = cnt_node[node];
        cnt = cnt < CAP ? cnt : CAP;
        const int* b = bucket + (size_t)node * CAP;
        int i = 0;
        for (; i + UN <= cnt; i += UN) {
            bf16x8 v[UN][KS1];
#pragma unroll
            for (int j = 0; j < UN; j++) {
                const unsigned short* r = hb + (size_t)b[i + j] * K_IN + quad * 8;
#pragma unroll
                for (int ks = 0; ks < KS1; ks++)
                    v[j][ks] = *(const bf16x8*)(r + ks * 32);
            }
            // pairwise tree accumulate (keeps ag chain shallow)
#pragma unroll
            for (int ks = 0; ks < KS1; ks++)
#pragma unroll
                for (int e = 0; e < 8; e++) {
                    float t01 = bf2f((unsigned short)v[0][ks][e]) +
                                bf2f((unsigned short)v[1][ks][e]);
                    float t23 = bf2f((unsigned short)v[2][ks][e]) +
                                bf2f((unsigned short)v[3][ks][e]);
                    float t = t01 + t23;
                    if (UN == 8) {
                        float t45 = bf2f((unsigned short)v[4][ks][e]) +
                                    bf2f((unsigned short)v[5][ks][e]);
                        float t67 = bf2f((unsigned short)v[6][ks][e]) +
                                    bf2f((unsigned short)v[7][ks][e]);
                        t += t45 + t67;
                    }
                    ag[ks][e] += t;
                }
        }
        for (; i < cnt; i++) {
            const unsigned short* r = hb + (size_t)b[i] * K_IN + quad * 8;
#pragma unroll
            for (int ks = 0; ks < KS1; ks++) {
                bf16x8 v = *(const bf16x8*)(r + ks * 32);
#pragma unroll
                for (int e = 0; e < 8; e++) ag[ks][e] += bf2f((unsigned short)v[e]);
            }
        }
#pragma unroll
        for (int ks = 0; ks < KS1; ks++) {
            bf16x8 vh, vl;
#pragma unroll
            for (int e = 0; e < 8; e++) {
                unsigned short hi, lo;
                split_bf16(ag[ks][e], hi, lo);
                vh[e] = (short)hi;
                vl[e] = (short)lo;
            }
            ah[s][ks] = vh;
            al[s][ks] = vl;
        }
    }

    f32x4 acc[2][8];

    // ---- stage 1 ----
#pragma unroll
    for (int nt = 0; nt < 8; nt++) {
        bf16x8 bh[KS1], bl[KS1];
#pragma unroll
        for (int ks = 0; ks < KS1; ks++) {
            bh[ks] = *(const bf16x8*)(w1h + ((nt * KS1 + ks) * 64 + lane) * 8);
            bl[ks] = *(const bf16x8*)(w1l + ((nt * KS1 + ks) * 64 + lane) * 8);
        }
        f32x4 c0 = {0.f, 0.f, 0.f, 0.f};
        f32x4 c1 = {0.f, 0.f, 0.f, 0.f};
#pragma unroll
        for (int ks = 0; ks < KS1; ks++) {
            c0 = __builtin_amdgcn_mfma_f32_16x16x32_bf16(ah[0][ks], bh[ks], c0, 0, 0, 0);
            c1 = __builtin_amdgcn_mfma_f32_16x16x32_bf16(ah[1][ks], bh[ks], c1, 0, 0, 0);
            c0 = __builtin_amdgcn_mfma_f32_16x16x32_bf16(al[0][ks], bh[ks], c0, 0, 0, 0);
            c1 = __builtin_amdgcn_mfma_f32_16x16x32_bf16(al[1][ks], bh[ks], c1, 0, 0, 0);
            c0 = __builtin_amdgcn_mfma_f32_16x16x32_bf16(ah[0][ks], bl[ks], c0, 0, 0, 0);
            c1 = __builtin_amdgcn_mfma_f32_16x16x32_bf16(ah[1][ks], bl[ks], c1, 0, 0, 0);
        }
        acc[0][nt] = c0;
        acc[1][nt] = c1;
    }

    // ---- transpose 1->2 through single LDS buffer: hi pass then lo pass ----
    bf16x8 a2h[2][4], a2l[2][4];
#pragma unroll
    for (int s = 0; s < 2; s++)
#pragma unroll
        for (int nt = 0; nt < 8; nt++) {
            float bj = b1[nt * 16 + m];
#pragma unroll
            for (int r = 0; r < 4; r++)
                sh[wave][s * 16 + quad * 4 + r][nt * 16 + m] =
                    bf16_hi(fmaxf(acc[s][nt][r] + bj, 0.f));
        }
#pragma unroll
    for (int s = 0; s < 2; s++)
#pragma unroll
        for (int ks = 0; ks < 4; ks++)
            a2h[s][ks] = *(const bf16x8*)&sh[wave][s * 16 + m][ks * 32 + quad * 8];
#pragma unroll
    for (int s = 0; s < 2; s++)
#pragma unroll
        for (int nt = 0; nt < 8; nt++) {
            float bj = b1[nt * 16 + m];
#pragma unroll
            for (int r = 0; r < 4; r++)
                sh[wave][s * 16 + quad * 4 + r][nt * 16 + m] =
                    bf16_lo(fmaxf(acc[s][nt][r] + bj, 0.f));
        }
#pragma unroll
    for (int s = 0; s < 2; s++)
#pragma unroll
        for (int ks = 0; ks < 4; ks++)
            a2l[s][ks] = *(const bf16x8*)&sh[wave][s * 16 + m][ks * 32 + quad * 8];

    // ---- stage 2 ----
#pragma unroll
    for (int nt = 0; nt < 8; nt++) {
        bf16x8 bh[4], bl[4];
#pragma unroll
        for (int ks = 0; ks < 4; ks++) {
            bh[ks] = *(const bf16x8*)(w2h + ((nt * 4 + ks) * 64 + lane) * 8);
            bl[ks] = *(const bf16x8*)(w2l + ((nt * 4 + ks) * 64 + lane) * 8);
        }
        f32x4 c0 = {0.f, 0.f, 0.f, 0.f};
        f32x4 c1 = {0.f, 0.f, 0.f, 0.f};
#pragma unroll
        for (int ks = 0; ks < 4; ks++) {
            c0 = __builtin_amdgcn_mfma_f32_16x16x32_bf16(a2h[0][ks], bh[ks], c0, 0, 0, 0);
            c1 = __builtin_amdgcn_mfma_f32_16x16x32_bf16(a2h[1][ks], bh[ks], c1, 0, 0, 0);
            c0 = __builtin_amdgcn_mfma_f32_16x16x32_bf16(a2l[0][ks], bh[ks], c0, 0, 0, 0);
            c1 = __builtin_amdgcn_mfma_f32_16x16x32_bf16(a2l[1][ks], bh[ks], c1, 0, 0, 0);
            c0 = __builtin_amdgcn_mfma_f32_16x16x32_bf16(a2h[0][ks], bl[ks], c0, 0, 0, 0);
            c1 = __builtin_amdgcn_mfma_f32_16x16x32_bf16(a2h[1][ks], bl[ks], c1, 0, 0, 0);
        }
        acc[0][nt] = c0;
        acc[1][nt] = c1;
    }

    // ---- transpose 2->3 ----
#pragma unroll
    for (int s = 0; s < 2; s++)
#pragma unroll
        for (int nt = 0; nt < 8; nt++) {
            float bj = b2[nt * 16 + m];
#pragma unroll
            for (int r = 0; r < 4; r++)
                sh[wave][s * 16 + quad * 4 + r][nt * 16 + m] =
                    bf16_hi(fmaxf(acc[s][nt][r] + bj, 0.f));
        }
#pragma unroll
    for (int s = 0; s < 2; s++)
#pragma unroll
        for (int ks = 0; ks < 4; ks++)
            a2h[s][ks] = *(const bf16x8*)&sh[wave][s * 16 + m][ks * 32 + quad * 8];
#pragma unroll
    for (int s = 0; s < 2; s++)
#pragma unroll
        for (int nt = 0; nt < 8; nt++) {
            float bj = b2[nt * 16 + m];
#pragma unroll
            for (int r = 0; r < 4; r++)
                sh[wave][s * 16 + quad * 4 + r][nt * 16 + m] =
                    bf16_lo(fmaxf(acc[s][nt][r] + bj, 0.f));
        }
#pragma unroll
    for (int s = 0; s < 2; s++)
#pragma unroll
        for (int ks = 0; ks < 4; ks++)
            a2l[s][ks] = *(const bf16x8*)&sh[wave][s * 16 + m][ks * 32 + quad * 8];

    // ---- stage 3 ----
#pragma unroll
    for (int nt = 0; nt < 8; nt++) {
        bf16x8 bh[4], bl[4];
#pragma unroll
        for (int ks = 0; ks < 4; ks++) {
            bh[ks] = *(const bf16x8*)(w3h + ((nt * 4 + ks) * 64 + lane) * 8);
            bl[ks] = *(const bf16x8*)(w3l + ((nt * 4 + ks) * 64 + lane) * 8);
        }
        f32x4 c0 = {0.f, 0.f, 0.f, 0.f};
        f32x4 c1 = {0.f, 0.f, 0.f, 0.f};
#pragma unroll
        for (int ks = 0; ks < 4; ks++) {
            c0 = __builtin_amdgcn_mfma_f32_16x16x32_bf16(a2h[0][ks], bh[ks], c0, 0, 0, 0);
            c1 = __builtin_amdgcn_mfma_f32_16x16x32_bf16(a2h[1][ks], bh[ks], c1, 0, 0, 0);
            c0 = __builtin_amdgcn_mfma_f32_16x16x32_bf16(a2l[0][ks], bh[ks], c0, 0, 0, 0);
            c1 = __builtin_amdgcn_mfma_f32_16x16x32_bf16(a2l[1][ks], bh[ks], c1, 0, 0, 0);
            c0 = __builtin_amdgcn_mfma_f32_16x16x32_bf16(a2h[0][ks], bl[ks], c0, 0, 0, 0);
            c1 = __builtin_amdgcn_mfma_f32_16x16x32_bf16(a2h[1][ks], bl[ks], c1, 0, 0, 0);
        }
        acc[0][nt] = c0;
        acc[1][nt] = c1;
    }

    if (POOL) {
        // ---- fused mean-pool epilogue: per-wave LDS run-length reduce ----
        float* shf = (float*)&sh[wave][0][0];
#pragma unroll
        for (int h = 0; h < 2; h++) {
#pragma unroll
            for (int nt = 0; nt < 8; nt++) {
                float bj = b3[nt * 16 + m];
#pragma unroll
                for (int r = 0; r < 4; r++)
                    shf[(quad * 4 + r) * 132 + nt * 16 + m] =
                        fmaxf(acc[h][nt][r] + bj, 0.f);
            }
            int c0 = lane * 2;
            float run0 = 0.f, run1 = 0.f;
            int gp = -1;
            for (int rrow = 0; rrow < 16; rrow++) {
                int node = nodeBase + h * 16 + rrow;
                if (node >= NN) break;
                int g = batch[node];
                float2 xv = *(const float2*)&shf[rrow * 132 + c0];
                if (g != gp) {
                    if (gp >= 0) {
                        atomicAdd(&pooled[(size_t)gp * HD + c0 + 0], run0);
                        atomicAdd(&pooled[(size_t)gp * HD + c0 + 1], run1);
                    }
                    run0 = xv.x; run1 = xv.y; gp = g;
                } else {
                    run0 += xv.x; run1 += xv.y;
                }
            }
            if (gp >= 0) {
                atomicAdd(&pooled[(size_t)gp * HD + c0 + 0], run0);
                atomicAdd(&pooled[(size_t)gp * HD + c0 + 1], run1);
            }
        }
    } else {
        // ---- epilogue: bf16 restage through LDS, coalesced row stores ----
#pragma unroll
        for (int s = 0; s < 2; s++)
#pragma unroll
            for (int nt = 0; nt < 8; nt++) {
                float bj = b3[nt * 16 + m];
#pragma unroll
                for (int r = 0; r < 4; r++)
                    sh[wave][s * 16 + quad * 4 + r][nt * 16 + m] =
                        bf16_hi(fmaxf(acc[s][nt][r] + bj, 0.f));
            }
#pragma unroll
        for (int io = 0; io < 8; io++) {
            int row32 = io * 4 + quad;
            int col = m * 8;
            int n2 = nodeBase + row32;
            bf16x8 v = *(const bf16x8*)&sh[wave][row32][col];
            if (n2 < NN) *(bf16x8*)&out[(size_t)n2 * HD + col] = v;
        }
    }
}

// ---------------------------------------------------------------------------
// Classifier head: one block (128 threads) per graph.
// ---------------------------------------------------------------------------
__launch_bounds__(128)
__global__ void head(const float* __restrict__ pooled, const int* __restrict__ cntg,
                     const float* __restrict__ fc0_w, const float* __restrict__ fc0_b,
                     const float* __restrict__ fc1_w, const float* __restrict__ fc1_b,
                     const float* __restrict__ out_w, const float* __restrict__ out_b,
                     float* __restrict__ out) {
    int g = blockIdx.x;
    int j = threadIdx.x;
    __shared__ float s0[HD];
    __shared__ float s1[HD];
    int c = cntg[g];
    float cf = (float)(c > 1 ? c : 1);
    s0[j] = pooled[(size_t)g * HD + j] / cf;
    __syncthreads();

    float acc = fc0_b[j];
    for (int k = 0; k < HD; k += 4) {
        float4 hv = *(const float4*)&s0[k];
        acc = fmaf(hv.x, fc0_w[(k + 0) * HD + j], acc);
        acc = fmaf(hv.y, fc0_w[(k + 1) * HD + j], acc);
        acc = fmaf(hv.z, fc0_w[(k + 2) * HD + j], acc);
        acc = fmaf(hv.w, fc0_w[(k + 3) * HD + j], acc);
    }
    s1[j] = fmaxf(acc, 0.0f);
    __syncthreads();

    acc = fc1_b[j];
    for (int k = 0; k < HD; k += 4) {
        float4 hv = *(const float4*)&s1[k];
        acc = fmaf(hv.x, fc1_w[(k + 0) * HD + j], acc);
        acc = fmaf(hv.y, fc1_w[(k + 1) * HD + j], acc);
        acc = fmaf(hv.z, fc1_w[(k + 2) * HD + j], acc);
        acc = fmaf(hv.w, fc1_w[(k + 3) * HD + j], acc);
    }
    float v = fmaxf(acc, 0.0f);

    float p0 = v * out_w[j * 2 + 0];
    float p1 = v * out_w[j * 2 + 1];
    __syncthreads();
    s0[j] = p0;
    s1[j] = p1;
    __syncthreads();
    for (int off = 64; off >= 1; off >>= 1) {
        if (j < off) {
            s0[j] += s0[j + off];
            s1[j] += s1[j + off];
        }
        __syncthreads();
    }
    if (j == 0) {
        out[(size_t)g * 2 + 0] = s0[0] + out_b[0];
        out[(size_t)g * 2 + 1] = s1[0] + out_b[1];
    }
}

// ---------------------------------------------------------------------------
extern "C" void kernel_launch(void* const* d_in, const int* in_sizes, int n_in,
                              void* d_out, int out_size, void* d_ws, size_t ws_size,
                              hipStream_t stream) {
    const float* x     = (const float*)d_in[0];
    const int*   ei    = (const int*)d_in[1];
    const int*   batch = (const int*)d_in[2];
    const float* cw[3][6];
    for (int i = 0; i < 3; i++)
        for (int k = 0; k < 6; k++) cw[i][k] = (const float*)d_in[3 + 6 * i + k];
    const float* fc0_w = (const float*)d_in[21];
    const float* fc0_b = (const float*)d_in[22];
    const float* fc1_w = (const float*)d_in[23];
    const float* fc1_b = (const float*)d_in[24];
    const float* out_w = (const float*)d_in[25];
    const float* out_b = (const float*)d_in[26];
    float* out = (float*)d_out;

    char* ws = (char*)d_ws;
    size_t off = 0;
    auto carve = [&](size_t bytes) {
        void* p = ws + off;
        off += (bytes + 255) & ~(size_t)255;
        return p;
    };
    int*   cnt_node = (int*)carve((size_t)NN * 4);
    int*   cntg     = (int*)carve((size_t)GG * 4);
    float* pooled   = (float*)carve((size_t)GG * HD * 4);
    int*   bucket   = (int*)carve((size_t)NN * CAP * 4);
    unsigned short* xb = (unsigned short*)carve((size_t)NP * F_IN * 2);
    unsigned short* hA = (unsigned short*)carve((size_t)NP * HD * 2);
    unsigned short* hB = (unsigned short*)carve((size_t)NP * HD * 2);
    unsigned short* wHi[9];
    unsigned short* wLo[9];
    int wK[9] = {F_IN, HD, HD, HD, HD, HD, HD, HD, HD};
    for (int i = 0; i < 9; i++) {
        wHi[i] = (unsigned short*)carve((size_t)wK[i] * HD * 2);
        wLo[i] = (unsigned short*)carve((size_t)wK[i] * HD * 2);
    }
    (void)ws_size;

    init_zero<<<(GG * HD + 255) / 256, 256, 0, stream>>>(cnt_node, cntg, pooled);
    convert_x<<<(NN * F_IN / 8 + 255) / 256, 256, 0, stream>>>(x, xb);
    build_graph<<<(EE + 255) / 256, 256, 0, stream>>>(ei, batch, cnt_node, cntg, bucket);

    PrepArgs pa;
    for (int l = 0; l < 3; l++)
        for (int s = 0; s < 3; s++) {
            int i = l * 3 + s;
            pa.d[i].src = cw[l][2 * s];
            pa.d[i].dhi = wHi[i];
            pa.d[i].dlo = wLo[i];
            pa.d[i].K = wK[i];
        }
    prep_weights<<<dim3(16, 9), 256, 0, stream>>>(pa);

    const int blocks = NP / 128;  // 1172

    // ---- GIN layer 0 (K=32, bf16 64B rows): xb -> hA (bf16) ----
    gin_layer<F_IN, false><<<blocks, 256, 0, stream>>>(xb, cnt_node, bucket,
        wHi[0], wLo[0], cw[0][1], wHi[1], wLo[1], cw[0][3], wHi[2], wLo[2], cw[0][5],
        hA, batch, pooled);
    // ---- GIN layer 1 (bf16): hA -> hB ----
    gin_layer<HD, false><<<blocks, 256, 0, stream>>>(hA, cnt_node, bucket,
        wHi[3], wLo[3], cw[1][1], wHi[4], wLo[4], cw[1][3], wHi[5], wLo[5], cw[1][5],
        hB, batch, pooled);
    // ---- GIN layer 2 (bf16, fused mean-pool): hB -> pooled ----
    gin_layer<HD, true><<<blocks, 256, 0, stream>>>(hB, cnt_node, bucket,
        wHi[6], wLo[6], cw[2][1], wHi[7], wLo[7], cw[2][3], wHi[8], wLo[8], cw[2][5],
        nullptr, batch, pooled);

    // ---- head ----
    head<<<GG, 128, 0, stream>>>(pooled, cntg, fc0_w, fc0_b, fc1_w, fc1_b, out_w, out_b, out);
}

// Round 16
// 546.866 us; speedup vs baseline: 1.0177x; 1.0177x over previous
//
#include <hip/hip_runtime.h>
#include <hip/hip_bf16.h>

// Problem constants (fixed by the reference)
#define NN 150000      // nodes
#define EE 600000      // edges
#define F_IN 32        // input node features
#define HD 128         // hidden dim
#define GG 2048        // graphs
#define CAP 28         // max degree bucket capacity (Poisson(4): P(deg>=28) ~ 4e-18)
#define NP 150016      // NN rounded up to 128-node blocks: 1172*128

typedef __attribute__((ext_vector_type(8))) short bf16x8;
typedef __attribute__((ext_vector_type(4))) float f32x4;

__device__ inline void split_bf16(float v, unsigned short& hi, unsigned short& lo) {
    __hip_bfloat16 h = __float2bfloat16(v);
    float hv = __bfloat162float(h);
    __hip_bfloat16 l = __float2bfloat16(v - hv);
    hi = *reinterpret_cast<unsigned short*>(&h);
    lo = *reinterpret_cast<unsigned short*>(&l);
}
__device__ inline unsigned short bf16_hi(float v) {
    __hip_bfloat16 h = __float2bfloat16(v);
    return *reinterpret_cast<unsigned short*>(&h);
}
__device__ inline unsigned short bf16_lo(float v) {
    __hip_bfloat16 h = __float2bfloat16(v);
    float hv = __bfloat162float(h);
    __hip_bfloat16 l = __float2bfloat16(v - hv);
    return *reinterpret_cast<unsigned short*>(&l);
}
__device__ inline float bf2f(unsigned short u) {
    union { unsigned int i; float f; } c;
    c.i = ((unsigned int)u) << 16;
    return c.f;
}

// ---------------------------------------------------------------------------
// Zero-init for workspace regions
// ---------------------------------------------------------------------------
__global__ void init_zero(int* __restrict__ cnt_node, int* __restrict__ cntg,
                          float* __restrict__ pooled) {
    int i = blockIdx.x * blockDim.x + threadIdx.x;
    if (i < NN) cnt_node[i] = 0;
    if (i < GG) cntg[i] = 0;
    if (i < GG * HD) pooled[i] = 0.f;
}

// ---------------------------------------------------------------------------
// CSR-bucket build + per-graph node counts (fused)
// ---------------------------------------------------------------------------
__global__ void build_graph(const int* __restrict__ ei, const int* __restrict__ batch,
                            int* __restrict__ cnt_node, int* __restrict__ cntg,
                            int* __restrict__ bucket) {
    int e = blockIdx.x * blockDim.x + threadIdx.x;
    if (e < NN) atomicAdd(&cntg[batch[e]], 1);
    if (e >= EE) return;
    int src = ei[e];         // edge_index[0]
    int dst = ei[EE + e];    // edge_index[1]
    int slot = atomicAdd(&cnt_node[dst], 1);
    if (slot < CAP) bucket[dst * CAP + slot] = src;
}

// ---------------------------------------------------------------------------
// Weight prep: fp32 W[K][H] -> split-bf16 packed in LANE-LINEAR fragment order
// ---------------------------------------------------------------------------
struct PrepDesc { const float* src; unsigned short* dhi; unsigned short* dlo; int K; };
struct PrepArgs { PrepDesc d[9]; };

__global__ void prep_weights(PrepArgs pa) {
    PrepDesc de = pa.d[blockIdx.y];
    int total = de.K * HD;
    int KS = de.K >> 5;
    for (int idx = blockIdx.x * blockDim.x + threadIdx.x; idx < total;
         idx += gridDim.x * blockDim.x) {
        int k = idx / HD, h = idx - (idx / HD) * HD;   // src is [K][H]
        unsigned short hi, lo;
        split_bf16(de.src[idx], hi, lo);
        int nt = h >> 4, m = h & 15;
        int ks = k >> 5, quad = (k >> 3) & 3, e = k & 7;
        int lane = quad * 16 + m;
        int pidx = ((nt * KS + ks) * 64 + lane) * 8 + e;
        de.dhi[pidx] = hi;
        de.dlo[pidx] = lo;
    }
}

// ---------------------------------------------------------------------------
// Fused GIN layer: gather-aggregate (fp32 accumulate) + 3-layer MLP on the
// matrix pipe, split-bf16 (hi+lo): D = Ah*Bh + Al*Bh + Ah*Bl (lo*lo dropped).
//
// FINAL (R12 config — best measured, 547.6 µs): bf16 inter-layer activations
// (256B rows), UN=4 gather unroll (8 for fp32 K=32 input), VGPR 84 at
// launch_bounds(256,3) — the empirically optimal waves x rows-in-flight
// point. Gather service rate is hardware-pinned at ~5.3G random rows/s
// (invariant across row bytes, unroll, registers, occupancy, chain depth,
// request granularity — R5..R15 falsification record).
// ---------------------------------------------------------------------------
template <int K_IN, bool BF16IN, bool POOL>
__launch_bounds__(256, 3)
__global__ void gin_layer(const void* __restrict__ hin_,
                          const int* __restrict__ cnt_node,
                          const int* __restrict__ bucket,
                          const unsigned short* __restrict__ w1h, const unsigned short* __restrict__ w1l,
                          const float* __restrict__ b1,
                          const unsigned short* __restrict__ w2h, const unsigned short* __restrict__ w2l,
                          const float* __restrict__ b2,
                          const unsigned short* __restrict__ w3h, const unsigned short* __restrict__ w3l,
                          const float* __restrict__ b3,
                          unsigned short* __restrict__ out,   // bf16 activations (non-pool)
                          const int* __restrict__ batch,
                          float* __restrict__ pooled) {
    constexpr int KS1 = K_IN / 32;
    constexpr int UN = BF16IN ? 4 : (KS1 == 1 ? 8 : 2);   // gather unroll depth
    __shared__ unsigned short sh[4][32][HD + 8];   // 34816 B / block

    const int wave = threadIdx.x >> 6;
    const int lane = threadIdx.x & 63;
    const int m = lane & 15;      // node row within a 16-set / out-feature col
    const int quad = lane >> 4;   // 0..3
    const int nodeBase = blockIdx.x * 128 + wave * 32;

    const float* hf = (const float*)hin_;
    const unsigned short* hb = (const unsigned short*)hin_;

    // ---- fused aggregation: self + neighbors, fp32 -> split-bf16 A frags ----
    bf16x8 ah[2][KS1], al[2][KS1];
#pragma unroll
    for (int s = 0; s < 2; s++) {
        int node = nodeBase + s * 16 + m;
        node = node < NN ? node : NN - 1;
        float ag[KS1][8];
        if (BF16IN) {
            const unsigned short* rs = hb + (size_t)node * K_IN + quad * 8;
#pragma unroll
            for (int ks = 0; ks < KS1; ks++) {
                bf16x8 v = *(const bf16x8*)(rs + ks * 32);
#pragma unroll
                for (int e = 0; e < 8; e++) ag[ks][e] = bf2f((unsigned short)v[e]);
            }
        } else {
            const float* rs = hf + (size_t)node * K_IN + quad * 8;
#pragma unroll
            for (int ks = 0; ks < KS1; ks++) {
                float4 v0 = *(const float4*)(rs + ks * 32);
                float4 v1 = *(const float4*)(rs + ks * 32 + 4);
                ag[ks][0] = v0.x; ag[ks][1] = v0.y; ag[ks][2] = v0.z; ag[ks][3] = v0.w;
                ag[ks][4] = v1.x; ag[ks][5] = v1.y; ag[ks][6] = v1.z; ag[ks][7] = v1.w;
            }
        }
        int cnt = cnt_node[node];
        cnt = cnt < CAP ? cnt : CAP;
        const int* b = bucket + (size_t)node * CAP;
        int i = 0;
        if (BF16IN) {
            for (; i + UN <= cnt; i += UN) {
                bf16x8 v[UN][KS1];
#pragma unroll
                for (int j = 0; j < UN; j++) {
                    const unsigned short* r = hb + (size_t)b[i + j] * K_IN + quad * 8;
#pragma unroll
                    for (int ks = 0; ks < KS1; ks++)
                        v[j][ks] = *(const bf16x8*)(r + ks * 32);
                }
#pragma unroll
                for (int ks = 0; ks < KS1; ks++)
#pragma unroll
                    for (int e = 0; e < 8; e++) {
                        float t01 = bf2f((unsigned short)v[0][ks][e]) +
                                    bf2f((unsigned short)v[1][ks][e]);
                        float t23 = bf2f((unsigned short)v[2][ks][e]) +
                                    bf2f((unsigned short)v[3][ks][e]);
                        ag[ks][e] += t01 + t23;
                    }
            }
            for (; i < cnt; i++) {
                const unsigned short* r = hb + (size_t)b[i] * K_IN + quad * 8;
#pragma unroll
                for (int ks = 0; ks < KS1; ks++) {
                    bf16x8 v = *(const bf16x8*)(r + ks * 32);
#pragma unroll
                    for (int e = 0; e < 8; e++) ag[ks][e] += bf2f((unsigned short)v[e]);
                }
            }
        } else {
            for (; i + UN <= cnt; i += UN) {
                float4 v0[UN][KS1], v1[UN][KS1];
#pragma unroll
                for (int j = 0; j < UN; j++) {
                    const float* r = hf + (size_t)b[i + j] * K_IN + quad * 8;
#pragma unroll
                    for (int ks = 0; ks < KS1; ks++) {
                        v0[j][ks] = *(const float4*)(r + ks * 32);
                        v1[j][ks] = *(const float4*)(r + ks * 32 + 4);
                    }
                }
#pragma unroll
                for (int ks = 0; ks < KS1; ks++) {
#pragma unroll
                    for (int e = 0; e < 4; e++) {
                        float s01 = (&v0[0][ks].x)[e] + (&v0[1][ks].x)[e];
                        float s23 = (&v0[2][ks].x)[e] + (&v0[3][ks].x)[e];
                        if (UN == 8) {
                            s01 += (&v0[4][ks].x)[e] + (&v0[5][ks].x)[e];
                            s23 += (&v0[6][ks].x)[e] + (&v0[7][ks].x)[e];
                        }
                        ag[ks][e] += s01 + s23;
                    }
#pragma unroll
                    for (int e = 0; e < 4; e++) {
                        float s01 = (&v1[0][ks].x)[e] + (&v1[1][ks].x)[e];
                        float s23 = (&v1[2][ks].x)[e] + (&v1[3][ks].x)[e];
                        if (UN == 8) {
                            s01 += (&v1[4][ks].x)[e] + (&v1[5][ks].x)[e];
                            s23 += (&v1[6][ks].x)[e] + (&v1[7][ks].x)[e];
                        }
                        ag[ks][e + 4] += s01 + s23;
                    }
                }
            }
            for (; i < cnt; i++) {
                const float* r = hf + (size_t)b[i] * K_IN + quad * 8;
#pragma unroll
                for (int ks = 0; ks < KS1; ks++) {
                    float4 v0 = *(const float4*)(r + ks * 32);
                    float4 v1 = *(const float4*)(r + ks * 32 + 4);
                    ag[ks][0] += v0.x; ag[ks][1] += v0.y; ag[ks][2] += v0.z; ag[ks][3] += v0.w;
                    ag[ks][4] += v1.x; ag[ks][5] += v1.y; ag[ks][6] += v1.z; ag[ks][7] += v1.w;
                }
            }
        }
#pragma unroll
        for (int ks = 0; ks < KS1; ks++) {
            bf16x8 vh, vl;
#pragma unroll
            for (int e = 0; e < 8; e++) {
                unsigned short hi, lo;
                split_bf16(ag[ks][e], hi, lo);
                vh[e] = (short)hi;
                vl[e] = (short)lo;
            }
            ah[s][ks] = vh;
            al[s][ks] = vl;
        }
    }

    f32x4 acc[2][8];

    // ---- stage 1 ----
#pragma unroll
    for (int nt = 0; nt < 8; nt++) {
        bf16x8 bh[KS1], bl[KS1];
#pragma unroll
        for (int ks = 0; ks < KS1; ks++) {
            bh[ks] = *(const bf16x8*)(w1h + ((nt * KS1 + ks) * 64 + lane) * 8);
            bl[ks] = *(const bf16x8*)(w1l + ((nt * KS1 + ks) * 64 + lane) * 8);
        }
        f32x4 c0 = {0.f, 0.f, 0.f, 0.f};
        f32x4 c1 = {0.f, 0.f, 0.f, 0.f};
#pragma unroll
        for (int ks = 0; ks < KS1; ks++) {
            c0 = __builtin_amdgcn_mfma_f32_16x16x32_bf16(ah[0][ks], bh[ks], c0, 0, 0, 0);
            c1 = __builtin_amdgcn_mfma_f32_16x16x32_bf16(ah[1][ks], bh[ks], c1, 0, 0, 0);
            c0 = __builtin_amdgcn_mfma_f32_16x16x32_bf16(al[0][ks], bh[ks], c0, 0, 0, 0);
            c1 = __builtin_amdgcn_mfma_f32_16x16x32_bf16(al[1][ks], bh[ks], c1, 0, 0, 0);
            c0 = __builtin_amdgcn_mfma_f32_16x16x32_bf16(ah[0][ks], bl[ks], c0, 0, 0, 0);
            c1 = __builtin_amdgcn_mfma_f32_16x16x32_bf16(ah[1][ks], bl[ks], c1, 0, 0, 0);
        }
        acc[0][nt] = c0;
        acc[1][nt] = c1;
    }

    // ---- transpose 1->2 through single LDS buffer: hi pass then lo pass ----
    bf16x8 a2h[2][4], a2l[2][4];
#pragma unroll
    for (int s = 0; s < 2; s++)
#pragma unroll
        for (int nt = 0; nt < 8; nt++) {
            float bj = b1[nt * 16 + m];
#pragma unroll
            for (int r = 0; r < 4; r++)
                sh[wave][s * 16 + quad * 4 + r][nt * 16 + m] =
                    bf16_hi(fmaxf(acc[s][nt][r] + bj, 0.f));
        }
#pragma unroll
    for (int s = 0; s < 2; s++)
#pragma unroll
        for (int ks = 0; ks < 4; ks++)
            a2h[s][ks] = *(const bf16x8*)&sh[wave][s * 16 + m][ks * 32 + quad * 8];
#pragma unroll
    for (int s = 0; s < 2; s++)
#pragma unroll
        for (int nt = 0; nt < 8; nt++) {
            float bj = b1[nt * 16 + m];
#pragma unroll
            for (int r = 0; r < 4; r++)
                sh[wave][s * 16 + quad * 4 + r][nt * 16 + m] =
                    bf16_lo(fmaxf(acc[s][nt][r] + bj, 0.f));
        }
#pragma unroll
    for (int s = 0; s < 2; s++)
#pragma unroll
        for (int ks = 0; ks < 4; ks++)
            a2l[s][ks] = *(const bf16x8*)&sh[wave][s * 16 + m][ks * 32 + quad * 8];

    // ---- stage 2 ----
#pragma unroll
    for (int nt = 0; nt < 8; nt++) {
        bf16x8 bh[4], bl[4];
#pragma unroll
        for (int ks = 0; ks < 4; ks++) {
            bh[ks] = *(const bf16x8*)(w2h + ((nt * 4 + ks) * 64 + lane) * 8);
            bl[ks] = *(const bf16x8*)(w2l + ((nt * 4 + ks) * 64 + lane) * 8);
        }
        f32x4 c0 = {0.f, 0.f, 0.f, 0.f};
        f32x4 c1 = {0.f, 0.f, 0.f, 0.f};
#pragma unroll
        for (int ks = 0; ks < 4; ks++) {
            c0 = __builtin_amdgcn_mfma_f32_16x16x32_bf16(a2h[0][ks], bh[ks], c0, 0, 0, 0);
            c1 = __builtin_amdgcn_mfma_f32_16x16x32_bf16(a2h[1][ks], bh[ks], c1, 0, 0, 0);
            c0 = __builtin_amdgcn_mfma_f32_16x16x32_bf16(a2l[0][ks], bh[ks], c0, 0, 0, 0);
            c1 = __builtin_amdgcn_mfma_f32_16x16x32_bf16(a2l[1][ks], bh[ks], c1, 0, 0, 0);
            c0 = __builtin_amdgcn_mfma_f32_16x16x32_bf16(a2h[0][ks], bl[ks], c0, 0, 0, 0);
            c1 = __builtin_amdgcn_mfma_f32_16x16x32_bf16(a2h[1][ks], bl[ks], c1, 0, 0, 0);
        }
        acc[0][nt] = c0;
        acc[1][nt] = c1;
    }

    // ---- transpose 2->3 ----
#pragma unroll
    for (int s = 0; s < 2; s++)
#pragma unroll
        for (int nt = 0; nt < 8; nt++) {
            float bj = b2[nt * 16 + m];
#pragma unroll
            for (int r = 0; r < 4; r++)
                sh[wave][s * 16 + quad * 4 + r][nt * 16 + m] =
                    bf16_hi(fmaxf(acc[s][nt][r] + bj, 0.f));
        }
#pragma unroll
    for (int s = 0; s < 2; s++)
#pragma unroll
        for (int ks = 0; ks < 4; ks++)
            a2h[s][ks] = *(const bf16x8*)&sh[wave][s * 16 + m][ks * 32 + quad * 8];
#pragma unroll
    for (int s = 0; s < 2; s++)
#pragma unroll
        for (int nt = 0; nt < 8; nt++) {
            float bj = b2[nt * 16 + m];
#pragma unroll
            for (int r = 0; r < 4; r++)
                sh[wave][s * 16 + quad * 4 + r][nt * 16 + m] =
                    bf16_lo(fmaxf(acc[s][nt][r] + bj, 0.f));
        }
#pragma unroll
    for (int s = 0; s < 2; s++)
#pragma unroll
        for (int ks = 0; ks < 4; ks++)
            a2l[s][ks] = *(const bf16x8*)&sh[wave][s * 16 + m][ks * 32 + quad * 8];

    // ---- stage 3 ----
#pragma unroll
    for (int nt = 0; nt < 8; nt++) {
        bf16x8 bh[4], bl[4];
#pragma unroll
        for (int ks = 0; ks < 4; ks++) {
            bh[ks] = *(const bf16x8*)(w3h + ((nt * 4 + ks) * 64 + lane) * 8);
            bl[ks] = *(const bf16x8*)(w3l + ((nt * 4 + ks) * 64 + lane) * 8);
        }
        f32x4 c0 = {0.f, 0.f, 0.f, 0.f};
        f32x4 c1 = {0.f, 0.f, 0.f, 0.f};
#pragma unroll
        for (int ks = 0; ks < 4; ks++) {
            c0 = __builtin_amdgcn_mfma_f32_16x16x32_bf16(a2h[0][ks], bh[ks], c0, 0, 0, 0);
            c1 = __builtin_amdgcn_mfma_f32_16x16x32_bf16(a2h[1][ks], bh[ks], c1, 0, 0, 0);
            c0 = __builtin_amdgcn_mfma_f32_16x16x32_bf16(a2l[0][ks], bh[ks], c0, 0, 0, 0);
            c1 = __builtin_amdgcn_mfma_f32_16x16x32_bf16(a2l[1][ks], bh[ks], c1, 0, 0, 0);
            c0 = __builtin_amdgcn_mfma_f32_16x16x32_bf16(a2h[0][ks], bl[ks], c0, 0, 0, 0);
            c1 = __builtin_amdgcn_mfma_f32_16x16x32_bf16(a2h[1][ks], bl[ks], c1, 0, 0, 0);
        }
        acc[0][nt] = c0;
        acc[1][nt] = c1;
    }

    if (POOL) {
        // ---- fused mean-pool epilogue: per-wave LDS run-length reduce ----
        float* shf = (float*)&sh[wave][0][0];
#pragma unroll
        for (int h = 0; h < 2; h++) {
#pragma unroll
            for (int nt = 0; nt < 8; nt++) {
                float bj = b3[nt * 16 + m];
#pragma unroll
                for (int r = 0; r < 4; r++)
                    shf[(quad * 4 + r) * 132 + nt * 16 + m] =
                        fmaxf(acc[h][nt][r] + bj, 0.f);
            }
            int c0 = lane * 2;
            float run0 = 0.f, run1 = 0.f;
            int gp = -1;
            for (int rrow = 0; rrow < 16; rrow++) {
                int node = nodeBase + h * 16 + rrow;
                if (node >= NN) break;
                int g = batch[node];
                float2 xv = *(const float2*)&shf[rrow * 132 + c0];
                if (g != gp) {
                    if (gp >= 0) {
                        atomicAdd(&pooled[(size_t)gp * HD + c0 + 0], run0);
                        atomicAdd(&pooled[(size_t)gp * HD + c0 + 1], run1);
                    }
                    run0 = xv.x; run1 = xv.y; gp = g;
                } else {
                    run0 += xv.x; run1 += xv.y;
                }
            }
            if (gp >= 0) {
                atomicAdd(&pooled[(size_t)gp * HD + c0 + 0], run0);
                atomicAdd(&pooled[(size_t)gp * HD + c0 + 1], run1);
            }
        }
    } else {
        // ---- epilogue: bf16 restage through LDS, coalesced row stores ----
#pragma unroll
        for (int s = 0; s < 2; s++)
#pragma unroll
            for (int nt = 0; nt < 8; nt++) {
                float bj = b3[nt * 16 + m];
#pragma unroll
                for (int r = 0; r < 4; r++)
                    sh[wave][s * 16 + quad * 4 + r][nt * 16 + m] =
                        bf16_hi(fmaxf(acc[s][nt][r] + bj, 0.f));
            }
#pragma unroll
        for (int io = 0; io < 8; io++) {
            int row32 = io * 4 + quad;
            int col = m * 8;
            int n2 = nodeBase + row32;
            bf16x8 v = *(const bf16x8*)&sh[wave][row32][col];
            if (n2 < NN) *(bf16x8*)&out[(size_t)n2 * HD + col] = v;
        }
    }
}

// ---------------------------------------------------------------------------
// Classifier head: one block (128 threads) per graph.
// ---------------------------------------------------------------------------
__launch_bounds__(128)
__global__ void head(const float* __restrict__ pooled, const int* __restrict__ cntg,
                     const float* __restrict__ fc0_w, const float* __restrict__ fc0_b,
                     const float* __restrict__ fc1_w, const float* __restrict__ fc1_b,
                     const float* __restrict__ out_w, const float* __restrict__ out_b,
                     float* __restrict__ out) {
    int g = blockIdx.x;
    int j = threadIdx.x;
    __shared__ float s0[HD];
    __shared__ float s1[HD];
    int c = cntg[g];
    float cf = (float)(c > 1 ? c : 1);
    s0[j] = pooled[(size_t)g * HD + j] / cf;
    __syncthreads();

    float acc = fc0_b[j];
    for (int k = 0; k < HD; k += 4) {
        float4 hv = *(const float4*)&s0[k];
        acc = fmaf(hv.x, fc0_w[(k + 0) * HD + j], acc);
        acc = fmaf(hv.y, fc0_w[(k + 1) * HD + j], acc);
        acc = fmaf(hv.z, fc0_w[(k + 2) * HD + j], acc);
        acc = fmaf(hv.w, fc0_w[(k + 3) * HD + j], acc);
    }
    s1[j] = fmaxf(acc, 0.0f);
    __syncthreads();

    acc = fc1_b[j];
    for (int k = 0; k < HD; k += 4) {
        float4 hv = *(const float4*)&s1[k];
        acc = fmaf(hv.x, fc1_w[(k + 0) * HD + j], acc);
        acc = fmaf(hv.y, fc1_w[(k + 1) * HD + j], acc);
        acc = fmaf(hv.z, fc1_w[(k + 2) * HD + j], acc);
        acc = fmaf(hv.w, fc1_w[(k + 3) * HD + j], acc);
    }
    float v = fmaxf(acc, 0.0f);

    float p0 = v * out_w[j * 2 + 0];
    float p1 = v * out_w[j * 2 + 1];
    __syncthreads();
    s0[j] = p0;
    s1[j] = p1;
    __syncthreads();
    for (int off = 64; off >= 1; off >>= 1) {
        if (j < off) {
            s0[j] += s0[j + off];
            s1[j] += s1[j + off];
        }
        __syncthreads();
    }
    if (j == 0) {
        out[(size_t)g * 2 + 0] = s0[0] + out_b[0];
        out[(size_t)g * 2 + 1] = s1[0] + out_b[1];
    }
}

// ---------------------------------------------------------------------------
extern "C" void kernel_launch(void* const* d_in, const int* in_sizes, int n_in,
                              void* d_out, int out_size, void* d_ws, size_t ws_size,
                              hipStream_t stream) {
    const float* x     = (const float*)d_in[0];
    const int*   ei    = (const int*)d_in[1];
    const int*   batch = (const int*)d_in[2];
    const float* cw[3][6];
    for (int i = 0; i < 3; i++)
        for (int k = 0; k < 6; k++) cw[i][k] = (const float*)d_in[3 + 6 * i + k];
    const float* fc0_w = (const float*)d_in[21];
    const float* fc0_b = (const float*)d_in[22];
    const float* fc1_w = (const float*)d_in[23];
    const float* fc1_b = (const float*)d_in[24];
    const float* out_w = (const float*)d_in[25];
    const float* out_b = (const float*)d_in[26];
    float* out = (float*)d_out;

    char* ws = (char*)d_ws;
    size_t off = 0;
    auto carve = [&](size_t bytes) {
        void* p = ws + off;
        off += (bytes + 255) & ~(size_t)255;
        return p;
    };
    int*   cnt_node = (int*)carve((size_t)NN * 4);
    int*   cntg     = (int*)carve((size_t)GG * 4);
    float* pooled   = (float*)carve((size_t)GG * HD * 4);
    int*   bucket   = (int*)carve((size_t)NN * CAP * 4);
    unsigned short* hA = (unsigned short*)carve((size_t)NP * HD * 2);
    unsigned short* hB = (unsigned short*)carve((size_t)NP * HD * 2);
    unsigned short* wHi[9];
    unsigned short* wLo[9];
    int wK[9] = {F_IN, HD, HD, HD, HD, HD, HD, HD, HD};
    for (int i = 0; i < 9; i++) {
        wHi[i] = (unsigned short*)carve((size_t)wK[i] * HD * 2);
        wLo[i] = (unsigned short*)carve((size_t)wK[i] * HD * 2);
    }
    (void)ws_size;

    init_zero<<<(GG * HD + 255) / 256, 256, 0, stream>>>(cnt_node, cntg, pooled);
    build_graph<<<(EE + 255) / 256, 256, 0, stream>>>(ei, batch, cnt_node, cntg, bucket);

    PrepArgs pa;
    for (int l = 0; l < 3; l++)
        for (int s = 0; s < 3; s++) {
            int i = l * 3 + s;
            pa.d[i].src = cw[l][2 * s];
            pa.d[i].dhi = wHi[i];
            pa.d[i].dlo = wLo[i];
            pa.d[i].K = wK[i];
        }
    prep_weights<<<dim3(16, 9), 256, 0, stream>>>(pa);

    const int blocks = NP / 128;  // 1172

    // ---- GIN layer 0 (K=32, fp32 in): x -> hA (bf16) ----
    gin_layer<F_IN, false, false><<<blocks, 256, 0, stream>>>(x, cnt_node, bucket,
        wHi[0], wLo[0], cw[0][1], wHi[1], wLo[1], cw[0][3], wHi[2], wLo[2], cw[0][5],
        hA, batch, pooled);
    // ---- GIN layer 1 (bf16 in): hA -> hB (bf16) ----
    gin_layer<HD, true, false><<<blocks, 256, 0, stream>>>(hA, cnt_node, bucket,
        wHi[3], wLo[3], cw[1][1], wHi[4], wLo[4], cw[1][3], wHi[5], wLo[5], cw[1][5],
        hB, batch, pooled);
    // ---- GIN layer 2 (bf16 in): hB -> pooled (fused mean-pool sum) ----
    gin_layer<HD, true, true><<<blocks, 256, 0, stream>>>(hB, cnt_node, bucket,
        wHi[6], wLo[6], cw[2][1], wHi[7], wLo[7], cw[2][3], wHi[8], wLo[8], cw[2][5],
        nullptr, batch, pooled);

    // ---- head ----
    head<<<GG, 128, 0, stream>>>(pooled, cntg, fc0_w, fc0_b, fc1_w, fc1_b, out_w, out_b, out);
}